// Round 5
// baseline (185.832 us; speedup 1.0000x reference)
//
#include <hip/hip_runtime.h>
#include <hip/hip_bf16.h>

// SDF volume rendering (NeuS/VolSDF-style), float32 in/out.
//
//   alpha_i = 1 - exp(-beta * sigmoid(-sdf_i * beta))
//   t_i     = exp(-beta * sigmoid(-sdf_i*beta)) + 1e-10   (= 1-alpha+1e-10)
//   trans_i = exclusive cumprod of t ;  w_i = alpha_i * trans_i
//   depth   = sum w_i z_i ;  rgb_c = sum w_i rgb_{i,c}
//
// R5: R2/R3/R4 (three different structures) all pinned at 57us -> limiter is
// the per-wave cross-lane chain (~26 dependent bpermutes/2 rays) + tiny
// memory-per-wave (5.4KB), not global access pattern. New layout:
//   - lane owns 12 consecutive samples (3 float4s); 8 lanes per ray;
//     8 rays per wave64. Local cumprod = serial VALU (free), cross-lane
//     = 3-step width-8 scan + 1 shift + 12 reduce shuffles = 16 ops/wave
//     for 8 rays (6.5x less per ray than R3).
//   - 15 independent float4 loads per lane up-front (21.5KB/wave in flight).
//   - passthrough sdf/z stored straight from the loaded float4 regs.
// No LDS. __launch_bounds__(256,4) -> 128 VGPR cap for ~90 live.

#define SDFR_NS 96

__global__ __launch_bounds__(256, 4) void sdf_render_kernel(
    const float4* __restrict__ sdf4,    // [N*96/4]
    const float4* __restrict__ z4,      // [N*96/4]
    const float4* __restrict__ rgb4,    // [N*96*3/4]
    const int*    __restrict__ beta_p,  // scalar (int32, or f32 bit pattern)
    float*  __restrict__ out_depth,     // [N]
    float*  __restrict__ out_rgb,       // [N,3]
    float4* __restrict__ out_sdf4,      // [N*96/4]
    float4* __restrict__ out_z4,        // [N*96/4]
    int n_rays)
{
    const int t    = threadIdx.x;
    const int wave = t >> 6;
    const int lane = t & 63;
    const int seg  = lane >> 3;   // which of 8 rays in this wave
    const int sl   = lane & 7;    // lane within the ray (owns 12 samples)

    const int ray = blockIdx.x * 32 + wave * 8 + seg;
    if (ray >= n_rays) return;

    const int b4  = ray * (SDFR_NS / 4) + sl * 3;        // sdf/z float4 index
    const int rb4 = ray * (SDFR_NS * 3 / 4) + sl * 9;    // rgb   float4 index

    // ---- 15 independent float4 loads, all issued before any use ----
    float4 s[3], z[3], c[9];
    #pragma unroll
    for (int i = 0; i < 3; ++i) s[i] = sdf4[b4 + i];
    #pragma unroll
    for (int i = 0; i < 3; ++i) z[i] = z4[b4 + i];
    #pragma unroll
    for (int i = 0; i < 9; ++i) c[i] = rgb4[rb4 + i];

    // beta decode: small int is the value; huge magnitude is f32 bit pattern
    int bi = *beta_p;
    float beta;
    if (bi > 1000000 || bi < -1000000) {
        union { int i; float f; } u; u.i = bi; beta = u.f;
    } else {
        beta = (float)bi;
    }

    // ---- passthrough stores (bit-exact), straight from loaded regs ----
    #pragma unroll
    for (int i = 0; i < 3; ++i) out_sdf4[b4 + i] = s[i];
    #pragma unroll
    for (int i = 0; i < 3; ++i) out_z4[b4 + i] = z[i];

    // ---- per-sample alpha / t (independent, wave64-parallel VALU) ----
    const float* sf = (const float*)s;
    const float* zf = (const float*)z;
    const float* cf = (const float*)c;
    float tv[12], av[12];
    #pragma unroll
    for (int j = 0; j < 12; ++j) {
        const float e = __expf(-beta * __builtin_amdgcn_rcpf(1.0f + __expf(sf[j] * beta)));
        av[j] = 1.0f - e;
        tv[j] = e + 1e-10f;
    }

    // ---- local product, then width-8 exclusive shuffle scan ----
    float m = 1.0f;
    #pragma unroll
    for (int j = 0; j < 12; ++j) m *= tv[j];

    float scan = m;
    #pragma unroll
    for (int d = 1; d < 8; d <<= 1) {
        float v = __shfl_up(scan, d, 8);
        if (sl >= d) scan *= v;
    }
    float E = __shfl_up(scan, 1, 8);   // inclusive at sl-1
    if (sl == 0) E = 1.0f;             // exclusive prefix for this lane

    // ---- weights + per-lane partial sums (serial local prefix, cheap) ----
    float depth = 0.0f, r0 = 0.0f, r1 = 0.0f, r2 = 0.0f;
    float p = E;
    #pragma unroll
    for (int j = 0; j < 12; ++j) {
        const float w = av[j] * p;
        depth += w * zf[j];
        r0 += w * cf[3 * j + 0];
        r1 += w * cf[3 * j + 1];
        r2 += w * cf[3 * j + 2];
        p *= tv[j];
    }

    // ---- butterfly reduction across the 8-lane segment ----
    #pragma unroll
    for (int d = 4; d >= 1; d >>= 1) {
        depth += __shfl_xor(depth, d, 8);
        r0    += __shfl_xor(r0, d, 8);
        r1    += __shfl_xor(r1, d, 8);
        r2    += __shfl_xor(r2, d, 8);
    }

    if (sl == 0) {
        out_depth[ray]       = depth;
        out_rgb[ray * 3 + 0] = r0;
        out_rgb[ray * 3 + 1] = r1;
        out_rgb[ray * 3 + 2] = r2;
    }
}

extern "C" void kernel_launch(void* const* d_in, const int* in_sizes, int n_in,
                              void* d_out, int out_size, void* d_ws, size_t ws_size,
                              hipStream_t stream) {
    (void)n_in; (void)d_ws; (void)ws_size; (void)out_size;

    const float4* rgb4   = (const float4*)d_in[0];
    const float4* sdf4   = (const float4*)d_in[1];
    const float4* z4     = (const float4*)d_in[2];
    const int*    beta_p = (const int*)d_in[3];

    const int n_rays = in_sizes[1] / SDFR_NS;  // 65536

    // output layout (f32): depth[N] | rgb[N*3] | sdf[N*96] | z[N*96]
    float* out_depth = (float*)d_out;
    float* out_rgb   = out_depth + n_rays;
    float* out_sdf   = out_rgb   + (size_t)n_rays * 3;
    float* out_z     = out_sdf   + (size_t)n_rays * SDFR_NS;

    // 8 rays/wave, 4 waves/block -> 32 rays/block
    const int grid = (n_rays + 31) / 32;  // 2048
    sdf_render_kernel<<<grid, 256, 0, stream>>>(
        sdf4, z4, rgb4, beta_p, out_depth, out_rgb,
        (float4*)out_sdf, (float4*)out_z, n_rays);
}

// Round 6
// 170.061 us; speedup vs baseline: 1.0927x; 1.0927x over previous
//
#include <hip/hip_runtime.h>
#include <hip/hip_bf16.h>

// SDF volume rendering (NeuS/VolSDF-style), float32 in/out.
//
//   alpha_i = 1 - exp(-beta * sigmoid(-sdf_i * beta))
//   t_i     = exp(-beta * sigmoid(-sdf_i*beta)) + 1e-10   (= 1-alpha+1e-10)
//   trans   = exclusive cumprod of t ;  w_i = alpha_i * trans_i
//   depth   = sum w_i z_i ;  rgb_c = sum w_i rgb_{i,c}
//
// R6: R2-R4 pinned at 57us (one-shot waves: one load burst then long
// memory-idle compute/drain tail -> request supply, not BW, limited to
// 2.0TB/s). R5 proved >2.5TB/s possible but its 48B-strided passthrough
// stores caused L2 write-allocate (+50MB FETCH). This version:
//  - 512 persistent blocks, grid-stride over 2048 tiles (32 rays/tile).
//  - sdf/z: coalesced float4 stream load -> coalesced passthrough store
//    (full cache lines) + LDS stage; NEXT tile's loads issued before the
//    compute phase and left in flight (software pipeline).
//  - rgb: direct consumer-layout loads (strided reads are HBM-benign, R5).
//  - barriers are lgkmcnt(0)+s_barrier only (no vmcnt drain -> prefetch
//    survives the barrier, unlike __syncthreads).
//  - compute: R5-validated math. 8 lanes/ray, 12 samples/lane, width-8
//    scan. LDS reads: uniform 8 words/bank = structural optimum.

#define SDFR_NS   96
#define SDFR_GRID 512          // 2 blocks/CU * 256 CU
#define SDFR_TILES 2048        // 65536 rays / 32 rays per tile

__device__ __forceinline__ void block_sync_light() {
    // barrier WITHOUT the vmcnt(0) drain __syncthreads would emit:
    // LDS visibility only; global prefetch loads stay in flight.
    asm volatile("s_waitcnt lgkmcnt(0)\n\ts_barrier" ::: "memory");
}

__global__ __launch_bounds__(256, 2) void sdf_render_kernel(
    const float4* __restrict__ sdf4,    // [N*96/4]
    const float4* __restrict__ z4,      // [N*96/4]
    const float4* __restrict__ rgb4,    // [N*96*3/4]
    const int*    __restrict__ beta_p,
    float*  __restrict__ out_depth,     // [N]
    float*  __restrict__ out_rgb,       // [N,3]
    float4* __restrict__ out_sdf4,      // [N*96/4]
    float4* __restrict__ out_z4,        // [N*96/4]
    int n_tiles)
{
    __shared__ float4 lds_s[768];   // 32 rays * 96 floats = 12KB
    __shared__ float4 lds_z[768];   // 12KB

    const int t    = threadIdx.x;
    const int wave = t >> 6;
    const int lane = t & 63;
    const int seg  = lane >> 3;     // 8 rays per wave
    const int sl   = lane & 7;      // lane within ray, owns 12 samples
    const int rl   = wave * 8 + seg;                 // local ray 0..31

    // beta decode: small int is the value; huge magnitude = f32 bit pattern
    int bi = *beta_p;
    float beta;
    if (bi > 1000000 || bi < -1000000) { union { int i; float f; } u; u.i = bi; beta = u.f; }
    else beta = (float)bi;

    int tile = blockIdx.x;
    float4 ps0, ps1, ps2, pz0, pz1, pz2;
    if (tile < n_tiles) {
        const int b = tile * 768 + t;
        ps0 = sdf4[b]; ps1 = sdf4[b + 256]; ps2 = sdf4[b + 512];
        pz0 = z4[b];   pz1 = z4[b + 256];   pz2 = z4[b + 512];
    }

    for (; tile < n_tiles; tile += SDFR_GRID) {
        const int b = tile * 768 + t;

        // ---- passthrough stores (full-line float4 streams) + LDS stage ----
        out_sdf4[b] = ps0; out_sdf4[b + 256] = ps1; out_sdf4[b + 512] = ps2;
        out_z4[b]   = pz0; out_z4[b + 256]   = pz1; out_z4[b + 512]   = pz2;
        lds_s[t] = ps0; lds_s[t + 256] = ps1; lds_s[t + 512] = ps2;
        lds_z[t] = pz0; lds_z[t + 256] = pz1; lds_z[t + 512] = pz2;
        block_sync_light();

        // ---- prefetch next tile; stays in flight through compute ----
        const int nt = tile + SDFR_GRID;
        if (nt < n_tiles) {
            const int nb = nt * 768 + t;
            ps0 = sdf4[nb]; ps1 = sdf4[nb + 256]; ps2 = sdf4[nb + 512];
            pz0 = z4[nb];   pz1 = z4[nb + 256];   pz2 = z4[nb + 512];
        }

        // ---- rgb in consumer layout (strided reads: HBM-benign) ----
        const int ray = tile * 32 + rl;
        const float4* rp = rgb4 + (size_t)ray * 72 + sl * 9;
        float4 c4[9];
        #pragma unroll
        for (int i = 0; i < 9; ++i) c4[i] = rp[i];

        // ---- LDS -> regs: this lane's 12 consecutive samples ----
        const int li = rl * 24 + sl * 3;
        float4 s4[3], zz4[3];
        #pragma unroll
        for (int i = 0; i < 3; ++i) { s4[i] = lds_s[li + i]; zz4[i] = lds_z[li + i]; }
        const float* sf = (const float*)s4;
        const float* zf = (const float*)zz4;
        const float* cf = (const float*)c4;

        // ---- alpha / t ----
        float tv[12], av[12];
        #pragma unroll
        for (int j = 0; j < 12; ++j) {
            const float e = __expf(-beta * __builtin_amdgcn_rcpf(1.0f + __expf(sf[j] * beta)));
            av[j] = 1.0f - e;
            tv[j] = e + 1e-10f;
        }

        // ---- local product + width-8 exclusive shuffle scan ----
        float m = 1.0f;
        #pragma unroll
        for (int j = 0; j < 12; ++j) m *= tv[j];
        float scan = m;
        #pragma unroll
        for (int d = 1; d < 8; d <<= 1) {
            float v = __shfl_up(scan, d, 8);
            if (sl >= d) scan *= v;
        }
        float E = __shfl_up(scan, 1, 8);
        if (sl == 0) E = 1.0f;

        // ---- weights + partial sums ----
        float depth = 0.0f, r0 = 0.0f, r1 = 0.0f, r2 = 0.0f;
        float p = E;
        #pragma unroll
        for (int j = 0; j < 12; ++j) {
            const float w = av[j] * p;
            depth += w * zf[j];
            r0 += w * cf[3 * j + 0];
            r1 += w * cf[3 * j + 1];
            r2 += w * cf[3 * j + 2];
            p *= tv[j];
        }

        // ---- butterfly reduction across the 8-lane segment ----
        #pragma unroll
        for (int d = 4; d >= 1; d >>= 1) {
            depth += __shfl_xor(depth, d, 8);
            r0    += __shfl_xor(r0, d, 8);
            r1    += __shfl_xor(r1, d, 8);
            r2    += __shfl_xor(r2, d, 8);
        }

        if (sl == 0) {
            out_depth[ray]       = depth;
            out_rgb[ray * 3 + 0] = r0;
            out_rgb[ray * 3 + 1] = r1;
            out_rgb[ray * 3 + 2] = r2;
        }

        block_sync_light();   // LDS consumed; safe to overwrite next iter
    }
}

extern "C" void kernel_launch(void* const* d_in, const int* in_sizes, int n_in,
                              void* d_out, int out_size, void* d_ws, size_t ws_size,
                              hipStream_t stream) {
    (void)n_in; (void)d_ws; (void)ws_size; (void)out_size;

    const float4* rgb4   = (const float4*)d_in[0];
    const float4* sdf4   = (const float4*)d_in[1];
    const float4* z4     = (const float4*)d_in[2];
    const int*    beta_p = (const int*)d_in[3];

    const int n_rays  = in_sizes[1] / SDFR_NS;  // 65536
    const int n_tiles = n_rays / 32;            // 2048

    // output layout (f32): depth[N] | rgb[N*3] | sdf[N*96] | z[N*96]
    float* out_depth = (float*)d_out;
    float* out_rgb   = out_depth + n_rays;
    float* out_sdf   = out_rgb   + (size_t)n_rays * 3;
    float* out_z     = out_sdf   + (size_t)n_rays * SDFR_NS;

    sdf_render_kernel<<<SDFR_GRID, 256, 0, stream>>>(
        sdf4, z4, rgb4, beta_p, out_depth, out_rgb,
        (float4*)out_sdf, (float4*)out_z, n_tiles);
}